// Round 7
// baseline (503.798 us; speedup 1.0000x reference)
//
#include <hip/hip_runtime.h>
#include <cstdint>

#define BB 4096
#define NV 20
#define CC 512
#define HH 256   // hidden
#define NC 40    // classes
#define SV 8     // selected views
#define GG 3     // batches per block
#define TAU 2e-4f

typedef short short8 __attribute__((ext_vector_type(8)));
typedef float f32x4 __attribute__((ext_vector_type(4)));
typedef unsigned short ushort8v __attribute__((ext_vector_type(8)));

__device__ __forceinline__ unsigned short f2bf(float x) {
    unsigned u = __float_as_uint(x);
    unsigned r = (u + 0x7FFFu + ((u >> 16) & 1u)) >> 16;
    return (unsigned short)r;
}
__device__ __forceinline__ float bf2f(unsigned short h) {
    return __uint_as_float(((unsigned)h) << 16);
}

#define MFMA16(A, B, C) __builtin_amdgcn_mfma_f32_16x16x32_bf16(A, B, C, 0, 0, 0)
#define BC8(x) __builtin_bit_cast(short8, x)

// ---------------------------------------------------------------------------
// Pack kernel (merged W1+W2): W1 [512][256] -> fragment-ordered bf16 hi/lo
//   e = ((ks*256 + n)*4 + kq)*8 + j3 ; k = ks*32 + kq*8 + j3
// W2 [256][40] -> padded N=48: e = ((ks*48+n)*4+kq)*8+j3
// Also zeroes the rescue worklist counter.
// ---------------------------------------------------------------------------
__global__ void pack_kernel(const float* __restrict__ W1,
                            const float* __restrict__ W2,
                            unsigned short* __restrict__ w1fh,
                            unsigned short* __restrict__ w1fl,
                            unsigned short* __restrict__ w2fh,
                            unsigned short* __restrict__ w2fl,
                            int* __restrict__ wcount) {
    int e = blockIdx.x * 256 + threadIdx.x;           // 131072 total
    if (e == 0) *wcount = 0;
    {
        int j3 = e & 7, kq = (e >> 3) & 3, n = (e >> 5) & 255, ks = e >> 13;
        int k = ks * 32 + kq * 8 + j3;
        float x = W1[k * HH + n];
        unsigned short h = f2bf(x);
        w1fh[e] = h;
        w1fl[e] = f2bf(x - bf2f(h));
    }
    if (e < 12288) {
        int j3 = e & 7, kq = (e >> 3) & 3;
        int t = e >> 5;
        int n = t % 48, ks = t / 48;
        int k = ks * 32 + kq * 8 + j3;
        float x = (n < NC) ? W2[k * NC + n] : 0.f;
        unsigned short h = f2bf(x);
        w2fh[e] = h;
        w2fl[e] = f2bf(x - bf2f(h));
    }
}

// ---------------------------------------------------------------------------
// Fused kernel. A-fragments are loaded per-lane DIRECTLY from global F0 and
// hi/lo-split in registers (lane (kq,l15) owns row mt*16+l15, 32B at col
// ks*32+kq*8) -> no A-LDS, no staging VALU round-trip, and ZERO barriers in
// the K-loop (no cross-wave dependency until layer-2). Accumulation order
// and split math identical to previous version -> bit-identical outputs.
// TAU-uncertain batches are appended to a compacted worklist for
// rescue_kernel (grid 256) which overwrites outF/outV.
// LDS: Hhi[32][264] @0 (16896B), Hlo @16896 (ends 33792),
//      Sc[3][840]f32 @33792 (ends 43872)
// ---------------------------------------------------------------------------
__global__ __launch_bounds__(256, 3) void fused_kernel(
    const float* __restrict__ F0, const float* __restrict__ V0,
    const float* __restrict__ b1, const float* __restrict__ b2,
    const unsigned short* __restrict__ w1fh, const unsigned short* __restrict__ w1fl,
    const unsigned short* __restrict__ w2fh, const unsigned short* __restrict__ w2fl,
    int* __restrict__ wcount, int* __restrict__ wl, int* __restrict__ rpred,
    float* __restrict__ outF, float* __restrict__ outS, float* __restrict__ outV)
{
    const int blk = blockIdx.x;
    const int j = threadIdx.x;
    const int L = j & 63, wq = j >> 6, l15 = L & 15, kq = L >> 4;

    __shared__ __align__(16) char lds[43872];
    __shared__ int idx8[GG][SV];

    unsigned short* Hhi = (unsigned short*)lds;             // [32][264]
    unsigned short* Hlo = Hhi + 32 * 264;                   // @16896
    float* Sc = (float*)(lds + 33792);                      // 3*840 f32

    // ---- layer-1 accumulators: acc[mt][nt], row g = mt*16+kq*4+reg (g<60),
    //      col = wq*64 + nt*16 + l15.  Row g -> batch g/20, view g%20.
    f32x4 acc[4][4];
#pragma unroll
    for (int mt = 0; mt < 4; ++mt)
#pragma unroll
        for (int nt = 0; nt < 4; ++nt) acc[mt][nt] = (f32x4){0.f, 0.f, 0.f, 0.f};

    // ---- per-lane A-row base pointers (fixed across ks) --------------------
    const float* arow[4];
    bool aval[4];
#pragma unroll
    for (int mt = 0; mt < 4; ++mt) {
        int g = mt * 16 + l15;
        aval[mt] = (g < 60);
        int bi = (g >= 40) ? 2 : (g >= 20) ? 1 : 0;
        int r = g - 20 * bi;
        if (!aval[mt]) r = 0;
        int batch = blk * GG + bi; if (batch > BB - 1) batch = BB - 1;
        arow[mt] = F0 + ((size_t)batch * NV + r) * CC;
    }

    const uint4* Bh = (const uint4*)w1fh;
    const uint4* Bl = (const uint4*)w1fl;

    // ---- K-loop: 16 ks steps, NO barriers ----------------------------------
#pragma unroll 2
    for (int ks = 0; ks < 16; ++ks) {
        uint4 bh[4], bl[4];
#pragma unroll
        for (int nt = 0; nt < 4; ++nt) {
            int bi1 = (ks * 256 + wq * 64 + nt * 16 + l15) * 4 + kq;
            bh[nt] = Bh[bi1]; bl[nt] = Bl[bi1];
        }
        short8 Ah[4], Al[4];
#pragma unroll
        for (int mt = 0; mt < 4; ++mt) {
            float4 x0 = {0.f, 0.f, 0.f, 0.f}, x1 = {0.f, 0.f, 0.f, 0.f};
            if (aval[mt]) {
                const float4* p = (const float4*)(arow[mt] + ks * 32 + kq * 8);
                x0 = p[0]; x1 = p[1];
            }
            float xs[8] = {x0.x, x0.y, x0.z, x0.w, x1.x, x1.y, x1.z, x1.w};
            ushort8v hv, lv;
#pragma unroll
            for (int i2 = 0; i2 < 8; ++i2) {
                unsigned short h = f2bf(xs[i2]);
                hv[i2] = h;
                lv[i2] = f2bf(xs[i2] - bf2f(h));
            }
            Ah[mt] = __builtin_bit_cast(short8, hv);
            Al[mt] = __builtin_bit_cast(short8, lv);
        }
#pragma unroll
        for (int mt = 0; mt < 4; ++mt)
#pragma unroll
            for (int nt = 0; nt < 4; ++nt) {
                short8 Bhv = BC8(bh[nt]), Blv = BC8(bl[nt]);
                acc[mt][nt] = MFMA16(Ah[mt], Bhv, acc[mt][nt]);
                acc[mt][nt] = MFMA16(Ah[mt], Blv, acc[mt][nt]);
                acc[mt][nt] = MFMA16(Al[mt], Bhv, acc[mt][nt]);
            }
    }

    // ---- layer 2: two rounds of 32 H-rows through LDS ----------------------
    // round p covers acc rows 32p..32p+31; in round 1, rows 28..30 of the H
    // buffer carry the 3 pooled rows (row 31 zeroed), giving Sc rows 60..62.
    const uint4* B2h = (const uint4*)w2fh;
    const uint4* B2l = (const uint4*)w2fl;
#pragma unroll
    for (int p = 0; p < 2; ++p) {
        __syncthreads();   // H region free (prev round reads done)
#pragma unroll
        for (int mt2 = 0; mt2 < 2; ++mt2) {
            int mt = 2 * p + mt2;
            bool skip = (p == 1 && mt2 == 1 && kq == 3);  // garbage rows 28..31
#pragma unroll
            for (int nt = 0; nt < 4; ++nt) {
                int col = wq * 64 + nt * 16 + l15;
                float bc = b1[col];
#pragma unroll
                for (int reg = 0; reg < 4; ++reg) {
                    int hb = mt2 * 16 + kq * 4 + reg;
                    float h = acc[mt][nt][reg] + bc;
                    h = (h > 0.f) ? h : 0.2f * h;
                    if (!skip) {
                        unsigned short hh = f2bf(h);
                        Hhi[hb * 264 + col] = hh;
                        Hlo[hb * 264 + col] = f2bf(h - bf2f(hh));
                    }
                }
            }
        }
        if (p == 1) {
            // pooled pre-activation = mean over the 20 view pre-activations
#pragma unroll
            for (int nt = 0; nt < 4; ++nt) {
                int col = wq * 64 + nt * 16 + l15;
                float p0 = 0.f, p1 = 0.f, p2 = 0.f;
#pragma unroll
                for (int mt = 0; mt < 4; ++mt)
#pragma unroll
                    for (int reg = 0; reg < 4; ++reg) {
                        int g = mt * 16 + kq * 4 + reg;
                        float v = acc[mt][nt][reg];
                        p0 += (g < 20) ? v : 0.f;
                        p1 += (g >= 20 && g < 40) ? v : 0.f;
                        p2 += (g >= 40 && g < 60) ? v : 0.f;
                    }
                p0 += __shfl_xor(p0, 16); p0 += __shfl_xor(p0, 32);
                p1 += __shfl_xor(p1, 16); p1 += __shfl_xor(p1, 32);
                p2 += __shfl_xor(p2, 16); p2 += __shfl_xor(p2, 32);
                if (kq < 3) {
                    float s = (kq == 0) ? p0 : (kq == 1) ? p1 : p2;
                    float h = s * (1.0f / NV) + b1[col];
                    h = (h > 0.f) ? h : 0.2f * h;
                    unsigned short hh = f2bf(h);
                    Hhi[(28 + kq) * 264 + col] = hh;
                    Hlo[(28 + kq) * 264 + col] = f2bf(h - bf2f(hh));
                } else {
                    Hhi[31 * 264 + col] = 0;
                    Hlo[31 * 264 + col] = 0;
                }
            }
        }
        __syncthreads();

        if (wq < 3) {
            f32x4 sacc[2];
            sacc[0] = (f32x4){0.f, 0.f, 0.f, 0.f};
            sacc[1] = (f32x4){0.f, 0.f, 0.f, 0.f};
            for (int ks2 = 0; ks2 < 8; ++ks2) {
                int bi2 = (ks2 * 48 + wq * 16 + l15) * 4 + kq;
                short8 Bhv = BC8(B2h[bi2]), Blv = BC8(B2l[bi2]);
#pragma unroll
                for (int tt = 0; tt < 2; ++tt) {
                    int off = (tt * 16 + l15) * 264 + ks2 * 32 + kq * 8;
                    short8 Ah2 = BC8(*(const uint4*)&Hhi[off]);
                    short8 Al2 = BC8(*(const uint4*)&Hlo[off]);
                    sacc[tt] = MFMA16(Ah2, Bhv, sacc[tt]);
                    sacc[tt] = MFMA16(Ah2, Blv, sacc[tt]);
                    sacc[tt] = MFMA16(Al2, Bhv, sacc[tt]);
                }
            }
            int cls = wq * 16 + l15;
            if (cls < NC) {
                float bc2 = b2[cls];
#pragma unroll
                for (int tt = 0; tt < 2; ++tt)
#pragma unroll
                    for (int reg = 0; reg < 4; ++reg) {
                        int lm = 32 * p + tt * 16 + kq * 4 + reg;
                        float sv = sacc[tt][reg] + bc2;
                        if (lm < 60) {
                            int bi = (lm >= 40) ? 2 : (lm >= 20) ? 1 : 0;
                            int r = lm - 20 * bi;
                            Sc[bi * 840 + r * NC + cls] = sv;
                        } else if (lm < 63) {
                            Sc[(lm - 60) * 840 + NV * NC + cls] = sv;  // pooled
                        }
                    }
            }
        }
    }
    __syncthreads();

    // ---- decisions + selection + worklist append (3 parallel lanes) --------
    if (j < GG) {
        const float* sp = &Sc[j * 840 + NV * NC];
        int p = 0;
        float m1 = sp[0];
        for (int c = 1; c < NC; ++c)
            if (sp[c] > m1) { m1 = sp[c]; p = c; }
        float m2 = -1e30f;
        for (int c = 0; c < NC; ++c)
            if (c != p && sp[c] > m2) m2 = sp[c];
        int f0 = (m1 - m2 < TAU) ? 1 : 0;

        float v[NV];
#pragma unroll
        for (int n = 0; n < NV; ++n) v[n] = Sc[j * 840 + n * NC + p];
        int ord[9];
        float vals[9];
        unsigned taken = 0;
#pragma unroll
        for (int s = 0; s < 9; ++s) {
            int bi = 0;
            float bv = -1e30f;
#pragma unroll
            for (int n = 0; n < NV; ++n)
                if (!((taken >> n) & 1u) && v[n] > bv) { bv = v[n]; bi = n; }
            taken |= 1u << bi;
            ord[s] = bi;
            vals[s] = bv;
        }
        int fix = 0;
#pragma unroll
        for (int s = 0; s < 8; ++s)
            if (vals[s] - vals[s + 1] < TAU) fix = 1;
#pragma unroll
        for (int s = 0; s < SV; ++s) idx8[j][s] = ord[s];

        int batch = blk * GG + j;
        if (batch < BB) {
            rpred[batch] = p;
            int flagv = f0 ? 1 : (fix ? 2 : 0);
            if (flagv) {
                int slot = atomicAdd(wcount, 1);
                wl[slot] = batch * 4 + flagv;
            }
        }
    }
    __syncthreads();

    // ---- epilogue -----------------------------------------------------------
    for (int t = j; t < GG * NV * NC; t += 256) {
        int bi = t / 800, o = t - bi * 800;
        int batch = blk * GG + bi; if (batch > BB - 1) batch = BB - 1;
        outS[(size_t)batch * (NV * NC) + o] = Sc[bi * 840 + o];
    }

    for (int t = j; t < GG * SV * (CC / 4); t += 256) {
        int bi = t >> 10;                 // /1024
        int s = (t >> 7) & 7;
        int t4 = t & 127;
        int batch = blk * GG + bi; if (batch > BB - 1) batch = BB - 1;
        int row = idx8[bi][s];
        const float4* src = (const float4*)(F0 + ((size_t)batch * NV + row) * CC);
        float4* dst = (float4*)(outF + ((size_t)batch * SV + s) * CC);
        dst[t4] = src[t4];
    }

    if (j < GG * SV * 3) {
        int bi = j / 24, o = j - bi * 24;
        int s = o / 3, d = o - s * 3;
        int batch = blk * GG + bi; if (batch > BB - 1) batch = BB - 1;
        outV[((size_t)batch * SV + s) * 3 + d] =
            V0[((size_t)batch * NV + idx8[bi][s]) * 3 + d];
    }
}

// ---------------------------------------------------------------------------
// Rescue kernel over the compacted worklist: grid 256 blocks, block i handles
// entries i, i+256, ... . flag==1: f64 pooled rescore -> pred. All flagged:
// f64 view rescore at pred (each thread owns hidden unit j, 20 rows in 2
// half-passes, wave-shuffle reduction), f64 top-8, overwrite outF/outV.
// ---------------------------------------------------------------------------
__global__ __launch_bounds__(256) void rescue_kernel(
    const float* __restrict__ F0, const float* __restrict__ V0,
    const float* __restrict__ W1, const float* __restrict__ b1,
    const float* __restrict__ W2, const float* __restrict__ b2,
    const int* __restrict__ wcount, const int* __restrict__ wl,
    const int* __restrict__ rpred,
    float* __restrict__ outF, float* __restrict__ outV)
{
    const int cnt = *wcount;
    if ((int)blockIdx.x >= cnt) return;

    const int j = threadIdx.x;
    const int L = j & 63, wq = j >> 6;

    __shared__ __align__(16) float Xf[NV * CC];   // 40960 B
    __shared__ double pooledD[CC];
    __shared__ double Dbuf[HH];
    __shared__ double Sd[NC];
    __shared__ double part[NV][4];
    __shared__ double SFdS[NV];
    __shared__ int predSh;
    __shared__ int idxs[SV];

    for (int w = blockIdx.x; w < cnt; w += 256) {
        const int e = wl[w];
        const int b = e >> 2;
        const int flag = e & 3;

        const float* Xb = F0 + (size_t)b * (NV * CC);
        for (int t = j; t < NV * CC / 4; t += 256)
            ((float4*)Xf)[t] = ((const float4*)Xb)[t];
        __syncthreads();

        if (flag == 1) {      // pred uncertain: f64 pooled rescore
            for (int c = j; c < CC; c += 256) {
                double s = 0.0;
                for (int r = 0; r < NV; ++r) s += (double)Xf[r * CC + c];
                pooledD[c] = s / (double)NV;
            }
            __syncthreads();
            double a = 0.0;
            for (int c = 0; c < CC; ++c) a += pooledD[c] * (double)W1[c * HH + j];
            double h = a + (double)b1[j];
            h = (h > 0.0) ? h : 0.2 * h;
            Dbuf[j] = h;
            __syncthreads();
            if (j < NC) {
                double s = 0.0;
                for (int k = 0; k < HH; ++k) s += Dbuf[k] * (double)W2[k * NC + j];
                Sd[j] = s + (double)b2[j];
            }
            __syncthreads();
            if (j == 0) {
                int p = 0;
                double m = Sd[0];
                for (int c = 1; c < NC; ++c)
                    if (Sd[c] > m) { m = Sd[c]; p = c; }
                predSh = p;
            }
            __syncthreads();
        } else {
            if (j == 0) predSh = rpred[b];
            __syncthreads();
        }
        const int p = predSh;

        const double b1d = (double)b1[j];
        const double w2jp = (double)W2[j * NC + p];
#pragma unroll
        for (int half = 0; half < 2; ++half) {
            double a[10];
#pragma unroll
            for (int r = 0; r < 10; ++r) a[r] = 0.0;
            for (int c = 0; c < CC; c += 4) {
                double w0 = (double)W1[(c + 0) * HH + j];
                double w1v = (double)W1[(c + 1) * HH + j];
                double w2v = (double)W1[(c + 2) * HH + j];
                double w3v = (double)W1[(c + 3) * HH + j];
#pragma unroll
                for (int r = 0; r < 10; ++r) {
                    const float4 x = *(const float4*)&Xf[(half * 10 + r) * CC + c];
                    a[r] += (double)x.x * w0;
                    a[r] += (double)x.y * w1v;
                    a[r] += (double)x.z * w2v;
                    a[r] += (double)x.w * w3v;
                }
            }
#pragma unroll
            for (int r = 0; r < 10; ++r) {
                double h = a[r] + b1d;
                h = (h > 0.0) ? h : 0.2 * h;
                double val = h * w2jp;
#pragma unroll
                for (int off = 32; off >= 1; off >>= 1)
                    val += __shfl_xor(val, off);
                if (L == 0) part[half * 10 + r][wq] = val;
            }
        }
        __syncthreads();
        if (j < NV)
            SFdS[j] = part[j][0] + part[j][1] + part[j][2] + part[j][3]
                    + (double)b2[p];
        __syncthreads();
        if (j == 0) {
            unsigned taken = 0;
            for (int s = 0; s < SV; ++s) {
                int bsel = 0;
                double bv = -1e300;
                for (int n = 0; n < NV; ++n)
                    if (!((taken >> n) & 1u) && SFdS[n] > bv) { bv = SFdS[n]; bsel = n; }
                taken |= 1u << bsel;
                idxs[s] = bsel;
            }
        }
        __syncthreads();

        for (int t = j; t < SV * (CC / 4); t += 256) {
            int s = t >> 7, t4 = t & 127;
            int row = idxs[s];
            ((float4*)(outF + ((size_t)b * SV + s) * CC))[t4] =
                ((const float4*)(F0 + ((size_t)b * NV + row) * CC))[t4];
        }
        if (j < SV * 3) {
            int s = j / 3, d = j - s * 3;
            outV[((size_t)b * SV + s) * 3 + d] =
                V0[((size_t)b * NV + idxs[s]) * 3 + d];
        }
        __syncthreads();
    }
}

// ---------------------------------------------------------------------------
extern "C" void kernel_launch(void* const* d_in, const int* in_sizes, int n_in,
                              void* d_out, int out_size, void* d_ws, size_t ws_size,
                              hipStream_t stream) {
    const float* F0 = (const float*)d_in[0];
    const float* V0 = (const float*)d_in[1];
    const float* W1 = (const float*)d_in[2];
    const float* b1 = (const float*)d_in[3];
    const float* W2 = (const float*)d_in[4];
    const float* b2 = (const float*)d_in[5];

    char* ws = (char*)d_ws;
    unsigned short* w1fh = (unsigned short*)ws;                   // 262144 B
    unsigned short* w1fl = (unsigned short*)(ws + 262144);        // 262144 B
    unsigned short* w2fh = (unsigned short*)(ws + 524288);        // 24576 B
    unsigned short* w2fl = (unsigned short*)(ws + 548864);        // 24576 B
    int* wcount = (int*)(ws + 573440);                            // 64 B
    int* wl     = (int*)(ws + 573504);                            // 16384 B
    int* rpred  = (int*)(ws + 589888);                            // 16384 B

    float* out = (float*)d_out;
    float* outF = out;                                // [4096,8,512]
    float* outS = out + (size_t)BB * SV * CC;         // [4096,20,40]
    float* outV = outS + (size_t)BB * NV * NC;        // [4096,8,3]

    pack_kernel<<<512, 256, 0, stream>>>(W1, W2, w1fh, w1fl, w2fh, w2fl, wcount);
    fused_kernel<<<(BB + GG - 1) / GG, 256, 0, stream>>>(
        F0, V0, b1, b2, w1fh, w1fl, w2fh, w2fl, wcount, wl, rpred,
        outF, outS, outV);
    rescue_kernel<<<256, 256, 0, stream>>>(
        F0, V0, W1, b1, W2, b2, wcount, wl, rpred, outF, outV);
}